// Round 16
// baseline (279.418 us; speedup 1.0000x reference)
//
#include <hip/hip_runtime.h>

#define BB 16      // batch
#define CC 64      // channels (Cin = Cout = 64)
#define HH 128
#define WW 128
#define MM 67      // modes per axis
#define MODES (MM*MM)   // 4489
#define MC 32      // mode chunk for mix
#define NCHUNK 141 // ceil(4489/32)

typedef float f4 __attribute__((ext_vector_type(4)));

#define AS1 __attribute__((address_space(1)))
#define AS3 __attribute__((address_space(3)))

__constant__ float DEC_LO[8] = {-0.010597401784997278f, 0.032883011666982945f, 0.030841381835986965f,
                                -0.18703481171888114f, -0.02798376941698385f, 0.6308807679295904f,
                                0.7148465705525415f, 0.23037781330885523f};
__constant__ float DEC_HI[8] = {-0.23037781330885523f, 0.7148465705525415f, -0.6308807679295904f,
                                -0.02798376941698385f, 0.18703481171888114f, 0.030841381835986965f,
                                -0.032883011666982945f, -0.010597401784997278f};

// ---------------- fused DWT: x (B,C,H,W) -> cf (B,C,4,67,67) ----------------
__global__ __launch_bounds__(256, 2) void dwt_f(const float* __restrict__ x, float* __restrict__ cf) {
    __shared__ float st[2][HH][MM];   // t1 [f][h][wo]  68,608 B
    const int bc  = blockIdx.x;
    const int tid = threadIdx.x;
    const float* xr = x + (size_t)bc * HH * WW;

    for (int p = tid; p < HH * MM; p += 256) {
        int wo = p % MM, h = p / MM;
        const float* row = xr + h * WW;
        float lo = 0.f, hi = 0.f;
        int base = 2 * wo - 6;
        #pragma unroll
        for (int k = 0; k < 8; ++k) {
            int i = base + k;
            i = (i < 0) ? (-i - 1) : i;
            i = (i >= WW) ? (2 * WW - 1 - i) : i;
            float v = row[i];
            lo += v * DEC_LO[7 - k];
            hi += v * DEC_HI[7 - k];
        }
        st[0][h][wo] = lo;
        st[1][h][wo] = hi;
    }
    __syncthreads();

    const int NH2 = (MM + 1) / 2;   // 34
    float* cfo = cf + (size_t)bc * 4 * MODES;
    for (int q = tid; q < NH2 * MM; q += 256) {
        int wo = q % MM, hp = q / MM;
        int ho0 = 2 * hp, ho1 = 2 * hp + 1;
        #pragma unroll
        for (int fw = 0; fw < 2; ++fw) {
            float rv[10];
            #pragma unroll
            for (int k = 0; k < 10; ++k) {
                int i = 4 * hp - 6 + k;
                i = (i < 0) ? (-i - 1) : i;
                i = (i >= HH) ? (2 * HH - 1 - i) : i;
                rv[k] = st[fw][i][wo];
            }
            float lo0 = 0.f, hi0 = 0.f, lo1 = 0.f, hi1 = 0.f;
            #pragma unroll
            for (int k = 0; k < 8; ++k) {
                lo0 += rv[k]     * DEC_LO[7 - k];
                hi0 += rv[k]     * DEC_HI[7 - k];
                lo1 += rv[k + 2] * DEC_LO[7 - k];
                hi1 += rv[k + 2] * DEC_HI[7 - k];
            }
            float* b0 = cfo + (size_t)(fw * 2 + 0) * MODES;
            float* b1 = cfo + (size_t)(fw * 2 + 1) * MODES;
            b0[ho0 * MM + wo] = lo0;
            b1[ho0 * MM + wo] = hi0;
            if (ho1 < MM) {
                b0[ho1 * MM + wo] = lo1;
                b1[ho1 * MM + wo] = hi1;
            }
        }
    }
}

// ---------------- per-mode channel mix ----------------
// out[b,o,band,m] = sum_i cf[b,i,band,m] * w_band[i,o,m]
// r6 compute shape (2 weight f4 -> 32 FMA/i, broadcast coeff reads) with the
// weight stream moved to a WAVE-PRIVATE 4-slot global_load_lds ring and
// counted vmcnt (never 0, no barriers in the loop) — T4. In-flight VMEM:
// 4 slots x 8 instr x 256 B = 8 KB/wave = 32 KB/CU, 4x the register-prefetch
// depth hipcc allowed r6 (8 KB/CU), which was its concurrency ceiling
// (2.1 TB/s effective weight stream at ~375 ns latency).
// LDS: 128 KB coeff + 32 KB ring = 160 KB exactly; 1 block/CU.
__global__ __launch_bounds__(256, 1) void mix_k(const float* __restrict__ cf,
                                                const float* __restrict__ w1,
                                                const float* __restrict__ w2,
                                                const float* __restrict__ w3,
                                                const float* __restrict__ w4,
                                                float* __restrict__ out) {
    __shared__ float sc[BB][CC][MC];          // coeff [b][i][m]   131072 B
    __shared__ float swr[4][4][16][MC];       // ring [wave][slot][row][m] 32768 B
    // --- bijective XCD swizzle over NWG = 141*4 = 564 = 8*70 + 4 ---
    int flat = blockIdx.y * NCHUNK + blockIdx.x;
    {
        const int q = 564 / 8, r = 564 % 8;          // 70, 4
        int xcd = flat & 7, j = flat >> 3;
        flat = (xcd < r ? xcd * (q + 1) : r * (q + 1) + (xcd - r) * q) + j;
    }
    const int band = flat / NCHUNK;
    const int m0   = min((flat % NCHUNK) * MC, MODES - MC);  // tail chunks overlap (identical values)
    const int tid  = threadIdx.x;
    const int lane = tid & 63, wv = tid >> 6;
    const float* w = (band == 0) ? w1 : (band == 1) ? w2 : (band == 2) ? w3 : w4;

    const int  ob0  = wv * 8;                         // wave's o-octet base
    const size_t IST = (size_t)CC * MODES;            // weight i-stride
    // per-lane DMA source base: row ob0 + (lane>>5), col lane&31
    const float* wbase = w + ((size_t)ob0 + (lane >> 5)) * MODES + m0 + (lane & 31);

    // Stage weights for cin=ii into ring slot: 16 rows (o: ob0..+8, ob0+32..+40)
    // x 32 floats = 2 KB = 8 instrs x 256 B. Dest linear (wave-uniform + lane*4).
    #define STAGE(slot, ii)                                                          \
    {                                                                                \
        const float* _s = wbase + (size_t)(ii) * IST;                                \
        _Pragma("unroll")                                                            \
        for (int _j = 0; _j < 8; ++_j) {                                             \
            __builtin_amdgcn_global_load_lds(                                        \
                (const AS1 void*)(_s + (size_t)(2 * _j + ((_j >= 4) ? 24 : 0)) * MODES), \
                (AS3 void*)&swr[wv][slot][2 * _j][0], 4, 0, 0);                      \
        }                                                                            \
    }

    // prologue: fill slots 0..3 (drained by the coeff-staging barrier below)
    STAGE(0, 0)
    STAGE(1, 1)
    STAGE(2, 2)
    STAGE(3, 3)

    // ---- stage coeff tile: 1024 rows (b*64+i) x 32 floats, 256 threads ----
    {
        const int c = tid & 7, r0 = tid >> 3;        // 8 threads/row
        #pragma unroll
        for (int p = 0; p < 32; ++p) {
            int r = r0 + (p << 5);                   // 0..1023
            f4 v = *(const f4*)(cf + ((size_t)(r * 4) + band) * MODES + m0 + c * 4);
            *(f4*)&sc[r >> 6][r & 63][c * 4] = v;
        }
    }
    __syncthreads();

    const int osub = lane >> 3;            // 0..7 -> o2 = ob0 + osub (and +32)
    const int m4q  = (lane & 7) * 4;       // float offset of this thread's 4 modes
    const int o2   = ob0 + osub;

    f4 accL[16], accH[16];
    #pragma unroll
    for (int b = 0; b < 16; ++b) { accL[b] = (f4)(0.f); accH[b] = (f4)(0.f); }

    #pragma unroll 1
    for (int i = 0; i < 60; ++i) {
        asm volatile("s_waitcnt vmcnt(24)" ::: "memory");   // oldest slot landed
        const int s = i & 3;
        f4 wl = *(const f4*)&swr[wv][s][osub][m4q];
        f4 wh = *(const f4*)&swr[wv][s][8 + osub][m4q];
        STAGE((i + 4) & 3, i + 4)                            // refill just-freed slot
        #pragma unroll
        for (int b = 0; b < 16; ++b) {
            f4 sv = *(const f4*)&sc[b][i][m4q];
            accL[b] += sv * wl;
            accH[b] += sv * wh;
        }
    }
    // tail: no more issues; counted drains 24 -> 16 -> 8 -> 0
    #define TAIL(ii, CNT)                                                   \
    {                                                                       \
        asm volatile("s_waitcnt vmcnt(" CNT ")" ::: "memory");              \
        const int s = (ii) & 3;                                             \
        f4 wl = *(const f4*)&swr[wv][s][osub][m4q];                         \
        f4 wh = *(const f4*)&swr[wv][s][8 + osub][m4q];                     \
        _Pragma("unroll")                                                   \
        for (int b = 0; b < 16; ++b) {                                      \
            f4 sv = *(const f4*)&sc[b][ii][m4q];                            \
            accL[b] += sv * wl;                                             \
            accH[b] += sv * wh;                                             \
        }                                                                   \
    }
    TAIL(60, "24")
    TAIL(61, "16")
    TAIL(62, "8")
    TAIL(63, "0")
    #undef TAIL
    #undef STAGE

    #pragma unroll
    for (int b = 0; b < 16; ++b) {
        *(f4*)&out[((size_t)((b * CC + o2) * 4) + band) * MODES + m0 + m4q] = accL[b];
        *(f4*)&out[((size_t)((b * CC + o2 + 32) * 4) + band) * MODES + m0 + m4q] = accH[b];
    }
}

// ---------------- fused IDWT: mixed (B,C,4,67,67) -> out (B,C,128,128) -------
__global__ __launch_bounds__(256, 2) void idwt_f(const float* __restrict__ mx, float* __restrict__ out) {
    __shared__ float su[2][HH][MM];   // u1 [fw][h][wo]  68,608 B
    const int bc  = blockIdx.x;
    const int tid = threadIdx.x;
    const float* mxb = mx + (size_t)bc * 4 * MODES;

    for (int p = tid; p < 2 * (HH / 2) * MM; p += 256) {
        int wo = p % MM;
        int a  = (p / MM) % (HH / 2);
        int fw = p / (MM * (HH / 2));
        const float* lo = mxb + (size_t)(fw * 2) * MODES + wo;
        const float* hi = lo + MODES;
        float l[4], h4[4];
        #pragma unroll
        for (int q = 0; q < 4; ++q) {
            l[q]  = lo[(a + q) * MM];
            h4[q] = hi[(a + q) * MM];
        }
        float o0 = 0.f, o1 = 0.f;
        #pragma unroll
        for (int q = 0; q < 4; ++q) {
            o0 += l[q] * DEC_LO[2 * q + 1] + h4[q] * DEC_HI[2 * q + 1];  // h = 2a
            o1 += l[q] * DEC_LO[2 * q]     + h4[q] * DEC_HI[2 * q];      // h = 2a+1
        }
        su[fw][2 * a][wo]     = o0;
        su[fw][2 * a + 1][wo] = o1;
    }
    __syncthreads();

    float* ob = out + (size_t)bc * HH * WW;
    for (int p = tid; p < HH * (WW / 2); p += 256) {
        int a = p & 63, h = p >> 6;
        float l[4], h4[4];
        #pragma unroll
        for (int q = 0; q < 4; ++q) {
            l[q]  = su[0][h][a + q];
            h4[q] = su[1][h][a + q];
        }
        float o0 = 0.f, o1 = 0.f;
        #pragma unroll
        for (int q = 0; q < 4; ++q) {
            o0 += l[q] * DEC_LO[2 * q + 1] + h4[q] * DEC_HI[2 * q + 1];  // n = 2a
            o1 += l[q] * DEC_LO[2 * q]     + h4[q] * DEC_HI[2 * q];      // n = 2a+1
        }
        *(float2*)&ob[h * WW + 2 * a] = make_float2(o0, o1);
    }
}

extern "C" void kernel_launch(void* const* d_in, const int* in_sizes, int n_in,
                              void* d_out, int out_size, void* d_ws, size_t ws_size,
                              hipStream_t stream) {
    const float* x  = (const float*)d_in[0];
    const float* w1 = (const float*)d_in[1];
    const float* w2 = (const float*)d_in[2];
    const float* w3 = (const float*)d_in[3];
    const float* w4 = (const float*)d_in[4];
    float* out = (float*)d_out;

    const size_t COEFF_FLTS = (size_t)BB * CC * 4 * MODES;
    float* buf1 = (float*)d_ws;            // coeff
    float* buf2 = buf1 + COEFF_FLTS;       // mixed

    // 1) fused DWT: x -> buf1 (coeff)
    dwt_f<<<BB * CC, 256, 0, stream>>>(x, buf1);
    // 2) per-mode channel mixing: buf1 -> buf2 (mixed)
    {
        dim3 grid(NCHUNK, 4);   // (141 mode-chunks, 4 bands)
        mix_k<<<grid, 256, 0, stream>>>(buf1, w1, w2, w3, w4, buf2);
    }
    // 3) fused IDWT: buf2 -> d_out
    idwt_f<<<BB * CC, 256, 0, stream>>>(buf2, out);
}

// Round 17
// 219.272 us; speedup vs baseline: 1.2743x; 1.2743x over previous
//
#include <hip/hip_runtime.h>

#define BB 16      // batch
#define CC 64      // channels (Cin = Cout = 64)
#define HH 128
#define WW 128
#define MM 67      // modes per axis
#define MODES (MM*MM)   // 4489
#define MC 32      // mode chunk for mix
#define NCHUNK 141 // ceil(4489/32)

typedef float f4 __attribute__((ext_vector_type(4)));

__constant__ float DEC_LO[8] = {-0.010597401784997278f, 0.032883011666982945f, 0.030841381835986965f,
                                -0.18703481171888114f, -0.02798376941698385f, 0.6308807679295904f,
                                0.7148465705525415f, 0.23037781330885523f};
__constant__ float DEC_HI[8] = {-0.23037781330885523f, 0.7148465705525415f, -0.6308807679295904f,
                                -0.02798376941698385f, 0.18703481171888114f, 0.030841381835986965f,
                                -0.032883011666982945f, -0.010597401784997278f};

// ---------------- fused DWT: x (B,C,H,W) -> cf (B,C,4,67,67) ----------------
// 512 threads (4 waves/SIMD at 2 blocks/CU) for latency hiding; t1 in LDS.
__global__ __launch_bounds__(512, 2) void dwt_f(const float* __restrict__ x, float* __restrict__ cf) {
    __shared__ float st[2][HH][MM];   // t1 [f][h][wo]  68,608 B
    const int bc  = blockIdx.x;
    const int tid = threadIdx.x;
    const float* xr = x + (size_t)bc * HH * WW;

    for (int p = tid; p < HH * MM; p += 512) {
        int wo = p % MM, h = p / MM;
        const float* row = xr + h * WW;
        float lo = 0.f, hi = 0.f;
        int base = 2 * wo - 6;
        #pragma unroll
        for (int k = 0; k < 8; ++k) {
            int i = base + k;
            i = (i < 0) ? (-i - 1) : i;
            i = (i >= WW) ? (2 * WW - 1 - i) : i;
            float v = row[i];
            lo += v * DEC_LO[7 - k];
            hi += v * DEC_HI[7 - k];
        }
        st[0][h][wo] = lo;
        st[1][h][wo] = hi;
    }
    __syncthreads();

    const int NH2 = (MM + 1) / 2;   // 34
    float* cfo = cf + (size_t)bc * 4 * MODES;
    for (int q = tid; q < NH2 * MM; q += 512) {
        int wo = q % MM, hp = q / MM;
        int ho0 = 2 * hp, ho1 = 2 * hp + 1;
        #pragma unroll
        for (int fw = 0; fw < 2; ++fw) {
            float rv[10];
            #pragma unroll
            for (int k = 0; k < 10; ++k) {
                int i = 4 * hp - 6 + k;
                i = (i < 0) ? (-i - 1) : i;
                i = (i >= HH) ? (2 * HH - 1 - i) : i;
                rv[k] = st[fw][i][wo];
            }
            float lo0 = 0.f, hi0 = 0.f, lo1 = 0.f, hi1 = 0.f;
            #pragma unroll
            for (int k = 0; k < 8; ++k) {
                lo0 += rv[k]     * DEC_LO[7 - k];
                hi0 += rv[k]     * DEC_HI[7 - k];
                lo1 += rv[k + 2] * DEC_LO[7 - k];
                hi1 += rv[k + 2] * DEC_HI[7 - k];
            }
            float* b0 = cfo + (size_t)(fw * 2 + 0) * MODES;
            float* b1 = cfo + (size_t)(fw * 2 + 1) * MODES;
            b0[ho0 * MM + wo] = lo0;
            b1[ho0 * MM + wo] = hi0;
            if (ho1 < MM) {
                b0[ho1 * MM + wo] = lo1;
                b1[ho1 * MM + wo] = hi1;
            }
        }
    }
}

// ---------------- per-mode channel mix (r13/r6 structure, 134 us — FROZEN) ----
// out[b,o,band,m] = sum_i cf[b,i,band,m] * w_band[i,o,m]
// Empirical optimum after 10 structural rewrites (rounds 5-16): 128 KB
// zero-redundancy coeff tile + 8-deep register weight prefetch (the only
// shape hipcc keeps live, VGPR=160). The ~2.2 TB/s effective weight stream
// is the DRAM efficiency of 128-B fragments at 17.9 KB stride — structural
// to the weight layout; every alternative (DMA rings, TLP variants, b/o/i
// splits, no-LDS) regressed.
__global__ __launch_bounds__(256) void mix_k(const float* __restrict__ cf,
                                             const float* __restrict__ w1,
                                             const float* __restrict__ w2,
                                             const float* __restrict__ w3,
                                             const float* __restrict__ w4,
                                             float* __restrict__ out) {
    __shared__ float sc[BB][CC][MC];   // [b][i][m] 128 KB
    // --- bijective XCD swizzle over NWG = 141*4 = 564 = 8*70 + 4 ---
    int flat = blockIdx.y * NCHUNK + blockIdx.x;
    {
        const int q = 564 / 8, r = 564 % 8;          // 70, 4
        int xcd = flat & 7, j = flat >> 3;
        flat = (xcd < r ? xcd * (q + 1) : r * (q + 1) + (xcd - r) * q) + j;
    }
    const int band = flat / NCHUNK;
    const int m0   = min((flat % NCHUNK) * MC, MODES - MC);
    const int tid  = threadIdx.x;
    const float* w = (band == 0) ? w1 : (band == 1) ? w2 : (band == 2) ? w3 : w4;

    // ---- stage coeff tile: 1024 rows (b*64+i) x 32 floats ----
    {
        const int c = tid & 7, r0 = tid >> 3;        // 8 threads/row
        #pragma unroll
        for (int p = 0; p < 32; ++p) {
            int r = r0 + (p << 5);                   // 0..1023
            f4 v = *(const f4*)(cf + ((size_t)(r * 4) + band) * MODES + m0 + c * 4);
            *(f4*)&sc[r >> 6][r & 63][c * 4] = v;
        }
    }
    __syncthreads();

    const int lane = tid & 63, wv = tid >> 6;
    const int o2 = wv * 8 + (lane >> 3);   // 0..31  (thread computes o2 and o2+32)
    const int mc4 = (lane & 7) * 4;        // mode sub-offset
    const size_t IST = (size_t)CC * MODES;
    const float* wpl = w + (size_t)o2 * MODES + m0 + mc4;
    const float* wph = wpl + (size_t)32 * MODES;

    f4 accL[16], accH[16];
    #pragma unroll
    for (int b = 0; b < 16; ++b) { accL[b] = (f4)(0.f); accH[b] = (f4)(0.f); }

    f4 al0, al1, al2, al3, ah0, ah1, ah2, ah3;
    f4 bl0, bl1, bl2, bl3, bh0, bh1, bh2, bh3;
    al0 = *(const f4*)(wpl + 0 * IST);  ah0 = *(const f4*)(wph + 0 * IST);
    al1 = *(const f4*)(wpl + 1 * IST);  ah1 = *(const f4*)(wph + 1 * IST);
    al2 = *(const f4*)(wpl + 2 * IST);  ah2 = *(const f4*)(wph + 2 * IST);
    al3 = *(const f4*)(wpl + 3 * IST);  ah3 = *(const f4*)(wph + 3 * IST);

    #pragma unroll 1
    for (int ib = 0; ib < 64; ib += 8) {
        bl0 = *(const f4*)(wpl + (size_t)(ib + 4) * IST);  bh0 = *(const f4*)(wph + (size_t)(ib + 4) * IST);
        bl1 = *(const f4*)(wpl + (size_t)(ib + 5) * IST);  bh1 = *(const f4*)(wph + (size_t)(ib + 5) * IST);
        bl2 = *(const f4*)(wpl + (size_t)(ib + 6) * IST);  bh2 = *(const f4*)(wph + (size_t)(ib + 6) * IST);
        bl3 = *(const f4*)(wpl + (size_t)(ib + 7) * IST);  bh3 = *(const f4*)(wph + (size_t)(ib + 7) * IST);
        #pragma unroll
        for (int b = 0; b < 16; ++b) {
            f4 s = *(const f4*)&sc[b][ib + 0][mc4];
            accL[b] += s * al0;  accH[b] += s * ah0;
        }
        #pragma unroll
        for (int b = 0; b < 16; ++b) {
            f4 s = *(const f4*)&sc[b][ib + 1][mc4];
            accL[b] += s * al1;  accH[b] += s * ah1;
        }
        #pragma unroll
        for (int b = 0; b < 16; ++b) {
            f4 s = *(const f4*)&sc[b][ib + 2][mc4];
            accL[b] += s * al2;  accH[b] += s * ah2;
        }
        #pragma unroll
        for (int b = 0; b < 16; ++b) {
            f4 s = *(const f4*)&sc[b][ib + 3][mc4];
            accL[b] += s * al3;  accH[b] += s * ah3;
        }
        if (ib + 8 < 64) {
            al0 = *(const f4*)(wpl + (size_t)(ib + 8)  * IST);  ah0 = *(const f4*)(wph + (size_t)(ib + 8)  * IST);
            al1 = *(const f4*)(wpl + (size_t)(ib + 9)  * IST);  ah1 = *(const f4*)(wph + (size_t)(ib + 9)  * IST);
            al2 = *(const f4*)(wpl + (size_t)(ib + 10) * IST);  ah2 = *(const f4*)(wph + (size_t)(ib + 10) * IST);
            al3 = *(const f4*)(wpl + (size_t)(ib + 11) * IST);  ah3 = *(const f4*)(wph + (size_t)(ib + 11) * IST);
        }
        #pragma unroll
        for (int b = 0; b < 16; ++b) {
            f4 s = *(const f4*)&sc[b][ib + 4][mc4];
            accL[b] += s * bl0;  accH[b] += s * bh0;
        }
        #pragma unroll
        for (int b = 0; b < 16; ++b) {
            f4 s = *(const f4*)&sc[b][ib + 5][mc4];
            accL[b] += s * bl1;  accH[b] += s * bh1;
        }
        #pragma unroll
        for (int b = 0; b < 16; ++b) {
            f4 s = *(const f4*)&sc[b][ib + 6][mc4];
            accL[b] += s * bl2;  accH[b] += s * bh2;
        }
        #pragma unroll
        for (int b = 0; b < 16; ++b) {
            f4 s = *(const f4*)&sc[b][ib + 7][mc4];
            accL[b] += s * bl3;  accH[b] += s * bh3;
        }
    }

    #pragma unroll
    for (int b = 0; b < 16; ++b) {
        *(f4*)&out[((size_t)((b * CC + o2) * 4) + band) * MODES + m0 + mc4] = accL[b];
        *(f4*)&out[((size_t)((b * CC + o2 + 32) * 4) + band) * MODES + m0 + mc4] = accH[b];
    }
}

// ---------------- fused IDWT: mixed (B,C,4,67,67) -> out (B,C,128,128) -------
// 512 threads (4 waves/SIMD at 2 blocks/CU); u1 in LDS.
__global__ __launch_bounds__(512, 2) void idwt_f(const float* __restrict__ mx, float* __restrict__ out) {
    __shared__ float su[2][HH][MM];   // u1 [fw][h][wo]  68,608 B
    const int bc  = blockIdx.x;
    const int tid = threadIdx.x;
    const float* mxb = mx + (size_t)bc * 4 * MODES;

    for (int p = tid; p < 2 * (HH / 2) * MM; p += 512) {
        int wo = p % MM;
        int a  = (p / MM) % (HH / 2);
        int fw = p / (MM * (HH / 2));
        const float* lo = mxb + (size_t)(fw * 2) * MODES + wo;
        const float* hi = lo + MODES;
        float l[4], h4[4];
        #pragma unroll
        for (int q = 0; q < 4; ++q) {
            l[q]  = lo[(a + q) * MM];
            h4[q] = hi[(a + q) * MM];
        }
        float o0 = 0.f, o1 = 0.f;
        #pragma unroll
        for (int q = 0; q < 4; ++q) {
            o0 += l[q] * DEC_LO[2 * q + 1] + h4[q] * DEC_HI[2 * q + 1];  // h = 2a
            o1 += l[q] * DEC_LO[2 * q]     + h4[q] * DEC_HI[2 * q];      // h = 2a+1
        }
        su[fw][2 * a][wo]     = o0;
        su[fw][2 * a + 1][wo] = o1;
    }
    __syncthreads();

    float* ob = out + (size_t)bc * HH * WW;
    for (int p = tid; p < HH * (WW / 2); p += 512) {
        int a = p & 63, h = p >> 6;
        float l[4], h4[4];
        #pragma unroll
        for (int q = 0; q < 4; ++q) {
            l[q]  = su[0][h][a + q];
            h4[q] = su[1][h][a + q];
        }
        float o0 = 0.f, o1 = 0.f;
        #pragma unroll
        for (int q = 0; q < 4; ++q) {
            o0 += l[q] * DEC_LO[2 * q + 1] + h4[q] * DEC_HI[2 * q + 1];  // n = 2a
            o1 += l[q] * DEC_LO[2 * q]     + h4[q] * DEC_HI[2 * q];      // n = 2a+1
        }
        *(float2*)&ob[h * WW + 2 * a] = make_float2(o0, o1);
    }
}

extern "C" void kernel_launch(void* const* d_in, const int* in_sizes, int n_in,
                              void* d_out, int out_size, void* d_ws, size_t ws_size,
                              hipStream_t stream) {
    const float* x  = (const float*)d_in[0];
    const float* w1 = (const float*)d_in[1];
    const float* w2 = (const float*)d_in[2];
    const float* w3 = (const float*)d_in[3];
    const float* w4 = (const float*)d_in[4];
    float* out = (float*)d_out;

    const size_t COEFF_FLTS = (size_t)BB * CC * 4 * MODES;
    float* buf1 = (float*)d_ws;            // coeff
    float* buf2 = buf1 + COEFF_FLTS;       // mixed

    // 1) fused DWT: x -> buf1 (coeff)
    dwt_f<<<BB * CC, 512, 0, stream>>>(x, buf1);
    // 2) per-mode channel mixing: buf1 -> buf2 (mixed)
    {
        dim3 grid(NCHUNK, 4);   // (141 mode-chunks, 4 bands)
        mix_k<<<grid, 256, 0, stream>>>(buf1, w1, w2, w3, w4, buf2);
    }
    // 3) fused IDWT: buf2 -> d_out
    idwt_f<<<BB * CC, 512, 0, stream>>>(buf2, out);
}

// Round 18
// 213.262 us; speedup vs baseline: 1.3102x; 1.0282x over previous
//
#include <hip/hip_runtime.h>

#define BB 16      // batch
#define CC 64      // channels (Cin = Cout = 64)
#define HH 128
#define WW 128
#define MM 67      // modes per axis
#define MODES (MM*MM)   // 4489
#define MC 32      // mode chunk for mix
#define NCHUNK 141 // ceil(4489/32)

typedef float f4 __attribute__((ext_vector_type(4)));

__constant__ float DEC_LO[8] = {-0.010597401784997278f, 0.032883011666982945f, 0.030841381835986965f,
                                -0.18703481171888114f, -0.02798376941698385f, 0.6308807679295904f,
                                0.7148465705525415f, 0.23037781330885523f};
__constant__ float DEC_HI[8] = {-0.23037781330885523f, 0.7148465705525415f, -0.6308807679295904f,
                                -0.02798376941698385f, 0.18703481171888114f, 0.030841381835986965f,
                                -0.032883011666982945f, -0.010597401784997278f};

// ---------------- fused DWT: x (B,C,H,W) -> cf (B,C,4,67,67) ----------------
// Phase A stages x rows through LDS (coalesced float2; VMEM instrs/thread
// 136 -> 16) and gathers the stride-2 taps from LDS where 2-way bank
// aliasing is free. t1 stays in LDS. 72.7 KB -> 2 blocks/CU at 512 threads.
__global__ __launch_bounds__(512, 2) void dwt_f(const float* __restrict__ x, float* __restrict__ cf) {
    __shared__ float st[2][HH][MM];   // t1 [f][h][wo]  68,608 B
    __shared__ float xs[8][WW];       // x row chunk     4,096 B
    const int bc  = blockIdx.x;
    const int tid = threadIdx.x;
    const float* xr = x + (size_t)bc * HH * WW;

    // Phase A: 16 chunks of 8 rows
    for (int ch = 0; ch < 16; ++ch) {
        {
            int r = tid >> 6;             // 0..7
            int c = (tid & 63) * 2;       // 0..126
            *(float2*)&xs[r][c] = *(const float2*)&xr[(size_t)(ch * 8 + r) * WW + c];
        }
        __syncthreads();
        for (int p = tid; p < 8 * MM; p += 512) {
            int wo = p % MM, r = p / MM;
            float lo = 0.f, hi = 0.f;
            int base = 2 * wo - 6;
            #pragma unroll
            for (int k = 0; k < 8; ++k) {
                int i = base + k;
                i = (i < 0) ? (-i - 1) : i;
                i = (i >= WW) ? (2 * WW - 1 - i) : i;
                float v = xs[r][i];
                lo += v * DEC_LO[7 - k];
                hi += v * DEC_HI[7 - k];
            }
            st[0][ch * 8 + r][wo] = lo;
            st[1][ch * 8 + r][wo] = hi;
        }
        __syncthreads();
    }

    // Phase B: H-transform from LDS (unchanged)
    const int NH2 = (MM + 1) / 2;   // 34
    float* cfo = cf + (size_t)bc * 4 * MODES;
    for (int q = tid; q < NH2 * MM; q += 512) {
        int wo = q % MM, hp = q / MM;
        int ho0 = 2 * hp, ho1 = 2 * hp + 1;
        #pragma unroll
        for (int fw = 0; fw < 2; ++fw) {
            float rv[10];
            #pragma unroll
            for (int k = 0; k < 10; ++k) {
                int i = 4 * hp - 6 + k;
                i = (i < 0) ? (-i - 1) : i;
                i = (i >= HH) ? (2 * HH - 1 - i) : i;
                rv[k] = st[fw][i][wo];
            }
            float lo0 = 0.f, hi0 = 0.f, lo1 = 0.f, hi1 = 0.f;
            #pragma unroll
            for (int k = 0; k < 8; ++k) {
                lo0 += rv[k]     * DEC_LO[7 - k];
                hi0 += rv[k]     * DEC_HI[7 - k];
                lo1 += rv[k + 2] * DEC_LO[7 - k];
                hi1 += rv[k + 2] * DEC_HI[7 - k];
            }
            float* b0 = cfo + (size_t)(fw * 2 + 0) * MODES;
            float* b1 = cfo + (size_t)(fw * 2 + 1) * MODES;
            b0[ho0 * MM + wo] = lo0;
            b1[ho0 * MM + wo] = hi0;
            if (ho1 < MM) {
                b0[ho1 * MM + wo] = lo1;
                b1[ho1 * MM + wo] = hi1;
            }
        }
    }
}

// ---------------- per-mode channel mix (r13/r6 structure, 134 us — FROZEN) ----
// out[b,o,band,m] = sum_i cf[b,i,band,m] * w_band[i,o,m]
// Empirical optimum after 11 structural rewrites (rounds 5-16).
__global__ __launch_bounds__(256) void mix_k(const float* __restrict__ cf,
                                             const float* __restrict__ w1,
                                             const float* __restrict__ w2,
                                             const float* __restrict__ w3,
                                             const float* __restrict__ w4,
                                             float* __restrict__ out) {
    __shared__ float sc[BB][CC][MC];   // [b][i][m] 128 KB
    // --- bijective XCD swizzle over NWG = 141*4 = 564 = 8*70 + 4 ---
    int flat = blockIdx.y * NCHUNK + blockIdx.x;
    {
        const int q = 564 / 8, r = 564 % 8;          // 70, 4
        int xcd = flat & 7, j = flat >> 3;
        flat = (xcd < r ? xcd * (q + 1) : r * (q + 1) + (xcd - r) * q) + j;
    }
    const int band = flat / NCHUNK;
    const int m0   = min((flat % NCHUNK) * MC, MODES - MC);
    const int tid  = threadIdx.x;
    const float* w = (band == 0) ? w1 : (band == 1) ? w2 : (band == 2) ? w3 : w4;

    // ---- stage coeff tile: 1024 rows (b*64+i) x 32 floats ----
    {
        const int c = tid & 7, r0 = tid >> 3;        // 8 threads/row
        #pragma unroll
        for (int p = 0; p < 32; ++p) {
            int r = r0 + (p << 5);                   // 0..1023
            f4 v = *(const f4*)(cf + ((size_t)(r * 4) + band) * MODES + m0 + c * 4);
            *(f4*)&sc[r >> 6][r & 63][c * 4] = v;
        }
    }
    __syncthreads();

    const int lane = tid & 63, wv = tid >> 6;
    const int o2 = wv * 8 + (lane >> 3);   // 0..31  (thread computes o2 and o2+32)
    const int mc4 = (lane & 7) * 4;        // mode sub-offset
    const size_t IST = (size_t)CC * MODES;
    const float* wpl = w + (size_t)o2 * MODES + m0 + mc4;
    const float* wph = wpl + (size_t)32 * MODES;

    f4 accL[16], accH[16];
    #pragma unroll
    for (int b = 0; b < 16; ++b) { accL[b] = (f4)(0.f); accH[b] = (f4)(0.f); }

    f4 al0, al1, al2, al3, ah0, ah1, ah2, ah3;
    f4 bl0, bl1, bl2, bl3, bh0, bh1, bh2, bh3;
    al0 = *(const f4*)(wpl + 0 * IST);  ah0 = *(const f4*)(wph + 0 * IST);
    al1 = *(const f4*)(wpl + 1 * IST);  ah1 = *(const f4*)(wph + 1 * IST);
    al2 = *(const f4*)(wpl + 2 * IST);  ah2 = *(const f4*)(wph + 2 * IST);
    al3 = *(const f4*)(wpl + 3 * IST);  ah3 = *(const f4*)(wph + 3 * IST);

    #pragma unroll 1
    for (int ib = 0; ib < 64; ib += 8) {
        bl0 = *(const f4*)(wpl + (size_t)(ib + 4) * IST);  bh0 = *(const f4*)(wph + (size_t)(ib + 4) * IST);
        bl1 = *(const f4*)(wpl + (size_t)(ib + 5) * IST);  bh1 = *(const f4*)(wph + (size_t)(ib + 5) * IST);
        bl2 = *(const f4*)(wpl + (size_t)(ib + 6) * IST);  bh2 = *(const f4*)(wph + (size_t)(ib + 6) * IST);
        bl3 = *(const f4*)(wpl + (size_t)(ib + 7) * IST);  bh3 = *(const f4*)(wph + (size_t)(ib + 7) * IST);
        #pragma unroll
        for (int b = 0; b < 16; ++b) {
            f4 s = *(const f4*)&sc[b][ib + 0][mc4];
            accL[b] += s * al0;  accH[b] += s * ah0;
        }
        #pragma unroll
        for (int b = 0; b < 16; ++b) {
            f4 s = *(const f4*)&sc[b][ib + 1][mc4];
            accL[b] += s * al1;  accH[b] += s * ah1;
        }
        #pragma unroll
        for (int b = 0; b < 16; ++b) {
            f4 s = *(const f4*)&sc[b][ib + 2][mc4];
            accL[b] += s * al2;  accH[b] += s * ah2;
        }
        #pragma unroll
        for (int b = 0; b < 16; ++b) {
            f4 s = *(const f4*)&sc[b][ib + 3][mc4];
            accL[b] += s * al3;  accH[b] += s * ah3;
        }
        if (ib + 8 < 64) {
            al0 = *(const f4*)(wpl + (size_t)(ib + 8)  * IST);  ah0 = *(const f4*)(wph + (size_t)(ib + 8)  * IST);
            al1 = *(const f4*)(wpl + (size_t)(ib + 9)  * IST);  ah1 = *(const f4*)(wph + (size_t)(ib + 9)  * IST);
            al2 = *(const f4*)(wpl + (size_t)(ib + 10) * IST);  ah2 = *(const f4*)(wph + (size_t)(ib + 10) * IST);
            al3 = *(const f4*)(wpl + (size_t)(ib + 11) * IST);  ah3 = *(const f4*)(wph + (size_t)(ib + 11) * IST);
        }
        #pragma unroll
        for (int b = 0; b < 16; ++b) {
            f4 s = *(const f4*)&sc[b][ib + 4][mc4];
            accL[b] += s * bl0;  accH[b] += s * bh0;
        }
        #pragma unroll
        for (int b = 0; b < 16; ++b) {
            f4 s = *(const f4*)&sc[b][ib + 5][mc4];
            accL[b] += s * bl1;  accH[b] += s * bh1;
        }
        #pragma unroll
        for (int b = 0; b < 16; ++b) {
            f4 s = *(const f4*)&sc[b][ib + 6][mc4];
            accL[b] += s * bl2;  accH[b] += s * bh2;
        }
        #pragma unroll
        for (int b = 0; b < 16; ++b) {
            f4 s = *(const f4*)&sc[b][ib + 7][mc4];
            accL[b] += s * bl3;  accH[b] += s * bh3;
        }
    }

    #pragma unroll
    for (int b = 0; b < 16; ++b) {
        *(f4*)&out[((size_t)((b * CC + o2) * 4) + band) * MODES + m0 + mc4] = accL[b];
        *(f4*)&out[((size_t)((b * CC + o2 + 32) * 4) + band) * MODES + m0 + mc4] = accH[b];
    }
}

// ---------------- fused IDWT: mixed (B,C,4,67,67) -> out (B,C,128,128) -------
// (r17 version, frozen)
__global__ __launch_bounds__(512, 2) void idwt_f(const float* __restrict__ mx, float* __restrict__ out) {
    __shared__ float su[2][HH][MM];   // u1 [fw][h][wo]  68,608 B
    const int bc  = blockIdx.x;
    const int tid = threadIdx.x;
    const float* mxb = mx + (size_t)bc * 4 * MODES;

    for (int p = tid; p < 2 * (HH / 2) * MM; p += 512) {
        int wo = p % MM;
        int a  = (p / MM) % (HH / 2);
        int fw = p / (MM * (HH / 2));
        const float* lo = mxb + (size_t)(fw * 2) * MODES + wo;
        const float* hi = lo + MODES;
        float l[4], h4[4];
        #pragma unroll
        for (int q = 0; q < 4; ++q) {
            l[q]  = lo[(a + q) * MM];
            h4[q] = hi[(a + q) * MM];
        }
        float o0 = 0.f, o1 = 0.f;
        #pragma unroll
        for (int q = 0; q < 4; ++q) {
            o0 += l[q] * DEC_LO[2 * q + 1] + h4[q] * DEC_HI[2 * q + 1];  // h = 2a
            o1 += l[q] * DEC_LO[2 * q]     + h4[q] * DEC_HI[2 * q];      // h = 2a+1
        }
        su[fw][2 * a][wo]     = o0;
        su[fw][2 * a + 1][wo] = o1;
    }
    __syncthreads();

    float* ob = out + (size_t)bc * HH * WW;
    for (int p = tid; p < HH * (WW / 2); p += 512) {
        int a = p & 63, h = p >> 6;
        float l[4], h4[4];
        #pragma unroll
        for (int q = 0; q < 4; ++q) {
            l[q]  = su[0][h][a + q];
            h4[q] = su[1][h][a + q];
        }
        float o0 = 0.f, o1 = 0.f;
        #pragma unroll
        for (int q = 0; q < 4; ++q) {
            o0 += l[q] * DEC_LO[2 * q + 1] + h4[q] * DEC_HI[2 * q + 1];  // n = 2a
            o1 += l[q] * DEC_LO[2 * q]     + h4[q] * DEC_HI[2 * q];      // n = 2a+1
        }
        *(float2*)&ob[h * WW + 2 * a] = make_float2(o0, o1);
    }
}

extern "C" void kernel_launch(void* const* d_in, const int* in_sizes, int n_in,
                              void* d_out, int out_size, void* d_ws, size_t ws_size,
                              hipStream_t stream) {
    const float* x  = (const float*)d_in[0];
    const float* w1 = (const float*)d_in[1];
    const float* w2 = (const float*)d_in[2];
    const float* w3 = (const float*)d_in[3];
    const float* w4 = (const float*)d_in[4];
    float* out = (float*)d_out;

    const size_t COEFF_FLTS = (size_t)BB * CC * 4 * MODES;
    float* buf1 = (float*)d_ws;            // coeff
    float* buf2 = buf1 + COEFF_FLTS;       // mixed

    // 1) fused DWT: x -> buf1 (coeff)
    dwt_f<<<BB * CC, 512, 0, stream>>>(x, buf1);
    // 2) per-mode channel mixing: buf1 -> buf2 (mixed)
    {
        dim3 grid(NCHUNK, 4);   // (141 mode-chunks, 4 bands)
        mix_k<<<grid, 256, 0, stream>>>(buf1, w1, w2, w3, w4, buf2);
    }
    // 3) fused IDWT: buf2 -> d_out
    idwt_f<<<BB * CC, 512, 0, stream>>>(buf2, out);
}